// Round 3
// baseline (524.989 us; speedup 1.0000x reference)
//
#include <hip/hip_runtime.h>
#include <hip/hip_bf16.h>
#include <math.h>

#define E 4
#define B 8192
#define F 2048
#define L 100
#define NROWS (E * B)          // 32768
#define LAMBDA 1.0f

typedef __attribute__((ext_vector_type(8))) short bf16x8;
typedef __attribute__((ext_vector_type(4))) float f32x4;

static __device__ inline unsigned short f2bf(float x) {
    unsigned u = __float_as_uint(x);
    unsigned r = (u + 0x7FFFu + ((u >> 16) & 1u)) >> 16;   // RNE
    return (unsigned short)r;
}

// ---- sums geometry ----
#define SG 4
#define NSG 25                 // 25 * 4 = 100 labels
#define SBS 8
#define SRW (B / SBS)          // 1024 rows per slice
#define NSUM (E * SBS * NSG)   // 800 blocks

// ---- gemm geometry ----
#define GBM 64                 // feats rows per block (4 waves x 16 rows)
#define NGEMM (NROWS / GBM)    // 512 blocks
#define NK (F / 32)            // 64 K-steps

// --------- K1: W[2048][100] f32 -> Wt[112][2048] bf16 (transposed+pad) ------
// Coalesced LDS-transpose; also folds all zero-init (replaces 2 memsets).
__global__ void __launch_bounds__(256) k_prep(const float* __restrict__ W,
                                              unsigned short* __restrict__ Wt,
                                              float* __restrict__ ce_accum,
                                              int* __restrict__ counts) {
    __shared__ float st[64][101];
    int t = threadIdx.x;
    int b = blockIdx.x;                      // 32 blocks, 64 k-rows each
    if (b == 0) {
        for (int i = t; i < E * L; i += 256) counts[i] = 0;
        if (t == 0) ce_accum[0] = 0.f;
    }
    int k0 = b * 64;
    for (int i = t; i < 64 * 100; i += 256) {
        st[i / 100][i % 100] = W[(size_t)k0 * L + i];
    }
    __syncthreads();
    for (int i = t; i < 112 * 32; i += 256) {
        int n = i >> 5, kp = i & 31;
        unsigned lo = 0, hi = 0;
        if (n < L) {
            lo = f2bf(st[kp * 2][n]);
            hi = f2bf(st[kp * 2 + 1][n]);
        }
        *(unsigned*)&Wt[(size_t)n * F + k0 + kp * 2] = lo | (hi << 16);
    }
}

// round-half-up pack of two f32 -> packed bf16x2 (hi<<16 | lo)
static __device__ inline unsigned pack_bf(float lo, float hi) {
    unsigned ul = __float_as_uint(lo) + 0x8000u;
    unsigned uh = __float_as_uint(hi) + 0x8000u;
    return __builtin_amdgcn_perm(uh, ul, 0x07060302u);
}

// ---- K2: merged main kernel. Blocks [0,512) = barrier-free deep-pipelined
// MFMA gemm+CE over 64 rows; blocks [512,1312) = tagged-stream label sums.
__global__ void __launch_bounds__(256, 3) k_main(const float* __restrict__ feats,
                                                 const int* __restrict__ y,
                                                 const unsigned short* __restrict__ Wt,
                                                 const float* __restrict__ bias,
                                                 float* __restrict__ partial,
                                                 int* __restrict__ counts,
                                                 float* __restrict__ ce_accum) {
    __shared__ __align__(16) char sm[6208];
    int t = threadIdx.x;

    if (blockIdx.x < NGEMM) {
        // ====== GEMM + CE: no LDS, no barriers, deep reg pipeline ======
        float* red = (float*)sm;                 // 4 floats
        int wave = t >> 6, lane = t & 63;
        int quad = lane >> 4, l16 = lane & 15;
        int row = blockIdx.x * GBM + wave * 16 + l16;   // this lane's feats row
        const float* ap = feats + (size_t)row * F + quad * 8;
        const unsigned short* wbase = Wt + (size_t)l16 * F + quad * 8;

        f32x4 acc[7];
#pragma unroll
        for (int ct = 0; ct < 7; ++ct) acc[ct] = (f32x4){0.f, 0.f, 0.f, 0.f};

        // A: 4-deep HBM pipeline (128 B/lane in flight). W: 2-deep L1/L2
        // pipeline (all 4 waves share the same 14 KB W-tile per step -> L1).
        float4 pa[4][2];
        bf16x8 pw[2][7];
#pragma unroll
        for (int j = 0; j < 4; ++j) {
            pa[j][0] = ((const float4*)(ap + j * 32))[0];
            pa[j][1] = ((const float4*)(ap + j * 32))[1];
        }
#pragma unroll
        for (int cw = 0; cw < 2; ++cw)
#pragma unroll
            for (int ct = 0; ct < 7; ++ct)
                pw[cw][ct] = *(const bf16x8*)(wbase + (size_t)ct * 16 * F + cw * 32);

        for (int k4 = 0; k4 < NK; k4 += 4) {
#pragma unroll
            for (int s = 0; s < 4; ++s) {        // all reg indices static
                int kk = k4 + s;
                union { unsigned w[4]; bf16x8 v; } bb;
                bb.w[0] = pack_bf(pa[s][0].x, pa[s][0].y);
                bb.w[1] = pack_bf(pa[s][0].z, pa[s][0].w);
                bb.w[2] = pack_bf(pa[s][1].x, pa[s][1].y);
                bb.w[3] = pack_bf(pa[s][1].z, pa[s][1].w);
                // refill A slot for kk+4 (tail: redundant in-bounds reload)
                int ka = (kk + 4 < NK) ? kk + 4 : NK - 1;
                pa[s][0] = ((const float4*)(ap + ka * 32))[0];
                pa[s][1] = ((const float4*)(ap + ka * 32))[1];
#pragma unroll
                for (int ct = 0; ct < 7; ++ct)
                    acc[ct] = __builtin_amdgcn_mfma_f32_16x16x32_bf16(pw[s & 1][ct], bb.v, acc[ct], 0, 0, 0);
                // refill W slot for kk+2
                int kw = (kk + 2 < NK) ? kk + 2 : NK - 1;
#pragma unroll
                for (int ct = 0; ct < 7; ++ct)
                    pw[s & 1][ct] = *(const bf16x8*)(wbase + (size_t)ct * 16 * F + kw * 32);
            }
        }

        // fused softmax-CE epilogue (D: lane&15 = feats row, col = 16*ct+quad*4+r)
        int lab = y[row];
        float vv[7][4];
        float vm = -1e30f;
#pragma unroll
        for (int ct = 0; ct < 7; ++ct) {
#pragma unroll
            for (int r = 0; r < 4; ++r) {
                int c = ct * 16 + quad * 4 + r;
                float bb2 = (c < L) ? bias[c] : 0.f;
                float v = acc[ct][r] + bb2;
                vv[ct][r] = v;
                if (c < L) vm = fmaxf(vm, v);
            }
        }
        vm = fmaxf(vm, __shfl_xor(vm, 16));
        vm = fmaxf(vm, __shfl_xor(vm, 32));
        float se = 0.f, tv = 0.f;
#pragma unroll
        for (int ct = 0; ct < 7; ++ct) {
#pragma unroll
            for (int r = 0; r < 4; ++r) {
                int c = ct * 16 + quad * 4 + r;
                if (c < L) se += __expf(vv[ct][r] - vm);
                if (c == lab) tv = vv[ct][r];
            }
        }
        se += __shfl_xor(se, 16);
        se += __shfl_xor(se, 32);
        tv += __shfl_xor(tv, 16);
        tv += __shfl_xor(tv, 32);
        float ce = vm + __logf(se) - tv;
#pragma unroll
        for (int s = 1; s <= 8; s <<= 1) ce += __shfl_xor(ce, s);
        if (lane == 0) red[wave] = ce;
        __syncthreads();
        if (t == 0) {
            float v = red[0] + red[1] + red[2] + red[3];
            atomicAdd(ce_accum, v);
        }
    } else {
        // ================= tagged-stream label sums (256 thr) =============
        int* ys = (int*)sm;                                   // 4096 B
        unsigned short* list = (unsigned short*)(sm + 4096);  // 2048 B
        int* cnt4 = (int*)(sm + 4096 + 2048);                 // 16 B
        int* ntot = (int*)(sm + 4096 + 2048 + 16);            // 4 B
        int bi = blockIdx.x - NGEMM;
        int lg = bi % NSG;
        int bs = (bi / NSG) % SBS;
        int e  = bi / (NSG * SBS);
        int lab0 = lg * SG;

        if (t < SG) cnt4[t] = 0;
        if (t == 8) ntot[0] = 0;
        const int* yb = y + e * B + bs * SRW;
#pragma unroll
        for (int j = 0; j < 4; ++j) ys[t + j * 256] = yb[t + j * 256];
        __syncthreads();

        for (int r = t; r < SRW; r += 256) {
            int lb = ys[r] - lab0;
            if ((unsigned)lb < SG) {
                atomicAdd(&cnt4[lb], 1);
                int p = atomicAdd(ntot, 1);
                list[p] = (unsigned short)(r | (lb << 10));
            }
        }
        __syncthreads();
        int n = ntot[0];
        int npad = (n + 3) & ~3;
        if (t < npad - n) list[n + t] = 0;   // pad rows (guarded out below)
        __syncthreads();

        // each thread owns 8 consecutive f32 (two float4) of the feature dim
        const float* fb = feats + ((size_t)e * B + (size_t)bs * SRW) * F + t * 8;
        float4 a0l = make_float4(0.f, 0.f, 0.f, 0.f), a0h = a0l;
        float4 a1l = a0l, a1h = a0l, a2l = a0l, a2h = a0l, a3l = a0l, a3h = a0l;

        float4 x[4][2];
        int tg[4];
        if (n > 0) {
#pragma unroll
            for (int j = 0; j < 4; ++j) {
                int ev = list[j];
                tg[j] = ev >> 10;
                const float* p = fb + (size_t)(ev & 1023) * F;
                x[j][0] = ((const float4*)p)[0];
                x[j][1] = ((const float4*)p)[1];
            }
            for (int i = 0; i < npad; i += 4) {
                float4 nx[4][2];
                int ntg[4];
                if (i + 4 < npad) {
#pragma unroll
                    for (int j = 0; j < 4; ++j) {
                        int ev = list[i + 4 + j];
                        ntg[j] = ev >> 10;
                        const float* p = fb + (size_t)(ev & 1023) * F;
                        nx[j][0] = ((const float4*)p)[0];
                        nx[j][1] = ((const float4*)p)[1];
                    }
                }
#pragma unroll
                for (int j = 0; j < 4; ++j) {
                    if (i + j < n) {   // uniform across block
                        float4 vl = x[j][0], vh = x[j][1];
                        int g = tg[j];  // uniform across block
                        if (g == 0) {
                            a0l.x += vl.x; a0l.y += vl.y; a0l.z += vl.z; a0l.w += vl.w;
                            a0h.x += vh.x; a0h.y += vh.y; a0h.z += vh.z; a0h.w += vh.w;
                        } else if (g == 1) {
                            a1l.x += vl.x; a1l.y += vl.y; a1l.z += vl.z; a1l.w += vl.w;
                            a1h.x += vh.x; a1h.y += vh.y; a1h.z += vh.z; a1h.w += vh.w;
                        } else if (g == 2) {
                            a2l.x += vl.x; a2l.y += vl.y; a2l.z += vl.z; a2l.w += vl.w;
                            a2h.x += vh.x; a2h.y += vh.y; a2h.z += vh.z; a2h.w += vh.w;
                        } else {
                            a3l.x += vl.x; a3l.y += vl.y; a3l.z += vl.z; a3l.w += vl.w;
                            a3h.x += vh.x; a3h.y += vh.y; a3h.z += vh.z; a3h.w += vh.w;
                        }
                    }
                }
#pragma unroll
                for (int j = 0; j < 4; ++j) {
                    x[j][0] = nx[j][0]; x[j][1] = nx[j][1]; tg[j] = ntg[j];
                }
            }
        }

        float* pb = partial + (((size_t)e * SBS + bs) * L + lab0) * F + t * 8;
        ((float4*)(pb + 0 * F))[0] = a0l;   // unconditional: partial is poisoned
        ((float4*)(pb + 0 * F))[1] = a0h;
        ((float4*)(pb + 1 * F))[0] = a1l;
        ((float4*)(pb + 1 * F))[1] = a1h;
        ((float4*)(pb + 2 * F))[0] = a2l;
        ((float4*)(pb + 2 * F))[1] = a2h;
        ((float4*)(pb + 3 * F))[0] = a3l;
        ((float4*)(pb + 3 * F))[1] = a3h;
        if (t < SG) atomicAdd(&counts[e * L + lab0 + t], cnt4[t]);
    }
}

// -------- K3: partial[e][bs][l][f] -> per-(e,l) variance over feature dim ---
__global__ void __launch_bounds__(512) k_var(const float* __restrict__ partial,
                                             const int* __restrict__ counts,
                                             float* __restrict__ var_out) {
    int el = blockIdx.x;  // e*L + l
    int e = el / L, l = el % L;
    int t = threadIdx.x;
    float inv = 1.f / fmaxf((float)counts[el], 1.f);
    float4 s = make_float4(0.f, 0.f, 0.f, 0.f);
#pragma unroll
    for (int bs = 0; bs < SBS; ++bs) {
        float4 v = *(const float4*)&partial[(((size_t)e * SBS + bs) * L + l) * F + t * 4];
        s.x += v.x; s.y += v.y; s.z += v.z; s.w += v.w;
    }
    float mx = s.x * inv, my = s.y * inv, mz = s.z * inv, mw = s.w * inv;
    float sm = mx + my + mz + mw;
    float sm2 = mx * mx + my * my + mz * mz + mw * mw;
#pragma unroll
    for (int sft = 1; sft <= 32; sft <<= 1) {
        sm += __shfl_xor(sm, sft);
        sm2 += __shfl_xor(sm2, sft);
    }
    __shared__ float r1[8], r2[8];
    int wv = t >> 6, ln = t & 63;
    if (ln == 0) { r1[wv] = sm; r2[wv] = sm2; }
    __syncthreads();
    if (t == 0) {
        float S = 0.f, S2 = 0.f;
#pragma unroll
        for (int w = 0; w < 8; ++w) { S += r1[w]; S2 += r2[w]; }
        var_out[el] = (S2 - S * S / (float)F) / (float)(F - 1);
    }
}

// ------------------------- K4: final scalar combine -------------------------
__global__ void k_final(const int* __restrict__ counts,
                        const float* __restrict__ var_in,
                        const float* __restrict__ ce_accum,
                        float* __restrict__ out) {
    __shared__ float s_sum[128], s_cnt[128];
    int t = threadIdx.x;
    float selsum = 0.f, selcnt = 0.f;
    for (int l = t; l < L; l += 128) {
        float nvis = 0.f, vsum = 0.f;
        for (int e = 0; e < E; ++e) {
            if (counts[e * L + l] > 0) { nvis += 1.f; vsum += var_in[e * L + l]; }
        }
        float per_label = vsum / fmaxf(nvis, 1.f);
        if (nvis > 1.5f) { selsum += per_label; selcnt += 1.f; }
    }
    s_sum[t] = selsum; s_cnt[t] = selcnt;
    __syncthreads();
    for (int s = 64; s > 0; s >>= 1) {
        if (t < s) { s_sum[t] += s_sum[t + s]; s_cnt[t] += s_cnt[t + s]; }
        __syncthreads();
    }
    if (t == 0) {
        float mean_loss = LAMBDA * s_sum[0] / fmaxf(s_cnt[0], 1.f);
        float ce = ce_accum[0] / (float)NROWS;
        out[0] = mean_loss + ce;
    }
}

extern "C" void kernel_launch(void* const* d_in, const int* in_sizes, int n_in,
                              void* d_out, int out_size, void* d_ws, size_t ws_size,
                              hipStream_t stream) {
    const float* feats = (const float*)d_in[0];
    const int*   y     = (const int*)d_in[1];
    const float* Wm    = (const float*)d_in[2];
    const float* bias  = (const float*)d_in[3];
    float* out = (float*)d_out;

    char* ws = (char*)d_ws;
    float*          ce_accum = (float*)ws;                  // 4 B
    int*            counts   = (int*)(ws + 256);            // 1600 B
    float*          var_buf  = (float*)(ws + 2048);         // 1600 B
    float*          partial  = (float*)(ws + 4096);         // E*SBS*L*F*4 = 26.2 MB
    unsigned short* Wt       = (unsigned short*)(ws + 4096 + (size_t)E * SBS * L * F * 4); // 458 KB

    k_prep<<<F / 64, 256, 0, stream>>>(Wm, Wt, ce_accum, counts);
    k_main<<<NGEMM + NSUM, 256, 0, stream>>>(feats, y, Wt, bias, partial, counts, ce_accum);
    k_var<<<E * L, 512, 0, stream>>>(partial, counts, var_buf);
    k_final<<<1, 128, 0, stream>>>(counts, var_buf, ce_accum, out);
}

// Round 4
// 413.234 us; speedup vs baseline: 1.2704x; 1.2704x over previous
//
#include <hip/hip_runtime.h>
#include <hip/hip_bf16.h>
#include <math.h>

#define E 4
#define B 8192
#define F 2048
#define L 100
#define NROWS (E * B)          // 32768
#define LAMBDA 1.0f

typedef __attribute__((ext_vector_type(8))) short bf16x8;
typedef __attribute__((ext_vector_type(4))) float f32x4;

static __device__ inline unsigned short f2bf(float x) {
    unsigned u = __float_as_uint(x);
    unsigned r = (u + 0x7FFFu + ((u >> 16) & 1u)) >> 16;   // RNE
    return (unsigned short)r;
}

// ---- sums geometry ----
#define SG 4
#define NSG 25                 // 25 * 4 = 100 labels
#define SBS 8
#define SRW (B / SBS)          // 1024 rows per slice
#define NSUM (E * SBS * NSG)   // 800 units

// ---- gemm geometry ----
#define GBM 32                 // feats rows per block (2 row-groups x 16)
#define GKC 64                 // k-chunk per staging step
#define APAD 72                // LDS row pitch (bf16) for As/Ws
#define NGEMM (NROWS / GBM)    // 1024 units
// grid interleave: 16-block tiles, 9 gemm + 7 sum each -> base 0..114
#define NBASE 115
#define NBLK (NBASE * 16)      // 1840

// --------- K1: W[2048][100] f32 -> Wt[112][2048] bf16 (transposed+pad) ------
__global__ void __launch_bounds__(256) k_prep(const float* __restrict__ W,
                                              unsigned short* __restrict__ Wt,
                                              float* __restrict__ ce_accum,
                                              int* __restrict__ counts) {
    __shared__ float st[64][101];
    int t = threadIdx.x;
    int b = blockIdx.x;                      // 32 blocks, 64 k-rows each
    if (b == 0) {
        for (int i = t; i < E * L; i += 256) counts[i] = 0;
        if (t == 0) ce_accum[0] = 0.f;
    }
    int k0 = b * 64;
    for (int i = t; i < 64 * 100; i += 256) {
        st[i / 100][i % 100] = W[(size_t)k0 * L + i];
    }
    __syncthreads();
    for (int i = t; i < 112 * 32; i += 256) {
        int n = i >> 5, kp = i & 31;
        unsigned lo = 0, hi = 0;
        if (n < L) {
            lo = f2bf(st[kp * 2][n]);
            hi = f2bf(st[kp * 2 + 1][n]);
        }
        *(unsigned*)&Wt[(size_t)n * F + k0 + kp * 2] = lo | (hi << 16);
    }
}

// round-half-up pack of two f32 -> packed bf16x2 (hi<<16 | lo)
static __device__ inline unsigned pack_bf(float lo, float hi) {
    unsigned ul = __float_as_uint(lo) + 0x8000u;
    unsigned uh = __float_as_uint(hi) + 0x8000u;
    return __builtin_amdgcn_perm(uh, ul, 0x07060302u);
}

// ---- K2: merged main kernel, 9:7 interleaved gemm/sum blocks.
// GEMM unit: 32 rows, 8 waves = 2 row-groups x 4 col-splits (ct {0,1}{2,3}{4,5}{6}).
__global__ void __launch_bounds__(512, 8) k_main(const float* __restrict__ feats,
                                                 const int* __restrict__ y,
                                                 const unsigned short* __restrict__ Wt,
                                                 const float* __restrict__ bias,
                                                 float* __restrict__ partial,
                                                 int* __restrict__ counts,
                                                 float* __restrict__ ce_accum) {
    __shared__ __align__(16) char sm[22400];
    int t = threadIdx.x;
    int u = blockIdx.x;
    int br = u & 15, base = u >> 4;

    if (br < 9) {
        int gid = base * 9 + br;
        if (gid >= NGEMM) return;
        // =============== GEMM + CE (LDS staged, col-split waves) ===========
        unsigned short* As = (unsigned short*)sm;            // 32*72*2 = 4608
        unsigned short* Ws = As + GBM * APAD;                // 112*72*2 = 16128
        float* pmaxs = (float*)(sm + 20736);                 // [4][32]
        float* psums = pmaxs + 128;                          // [4][32]
        float* ptgts = psums + 128;                          // [4][32]
        float* ceg   = ptgts + 128;                          // [2]
        int wave = t >> 6, lane = t & 63;
        int quad = lane >> 4, l16 = lane & 15;
        int g = wave >> 2, h = wave & 3;                     // row-group, col-split
        size_t row0 = (size_t)gid * GBM;

        // staging map: A: 16 thr/row, 256 B contiguous per row
        int arow = t >> 4, acol = (t & 15) * 4;
        const float* aptr = feats + (row0 + arow) * (size_t)F + acol;
        // W: slot s -> row s>>3, 8 bf16 at (s&7)*8 ; slots t and 512+t
        int w1row = t >> 3, w1c = (t & 7) * 8;
        int w2row = (512 + t) >> 3, w2c = ((512 + t) & 7) * 8;
        const unsigned short* wp1 = Wt + (size_t)w1row * F + w1c;
        const unsigned short* wp2 = (t < 384) ? Wt + (size_t)w2row * F + w2c : Wt;

        f32x4 acc0 = (f32x4){0.f, 0.f, 0.f, 0.f};
        f32x4 acc1 = acc0;

        float4 pa = *(const float4*)aptr;
        uint4 pw1 = *(const uint4*)wp1;
        uint4 pw2 = *(const uint4*)wp2;

        for (int k0 = 0; k0 < F; k0 += GKC) {
            __syncthreads();                 // readers of prev tile done
            unsigned u0 = pack_bf(pa.x, pa.y), u1 = pack_bf(pa.z, pa.w);
            *(uint2*)&As[arow * APAD + acol] = make_uint2(u0, u1);
            *(uint4*)&Ws[w1row * APAD + w1c] = pw1;
            if (t < 384) *(uint4*)&Ws[w2row * APAD + w2c] = pw2;
            __syncthreads();
            if (k0 + GKC < F) {              // prefetch next tile into regs
                pa  = *(const float4*)(aptr + k0 + GKC);
                pw1 = *(const uint4*)(wp1 + k0 + GKC);
                pw2 = *(const uint4*)(wp2 + k0 + GKC);
            }
#pragma unroll
            for (int ks = 0; ks < 2; ++ks) {
                bf16x8 bfr = *(const bf16x8*)&As[(g * 16 + l16) * APAD + ks * 32 + quad * 8];
                bf16x8 af0 = *(const bf16x8*)&Ws[((2 * h) * 16 + l16) * APAD + ks * 32 + quad * 8];
                acc0 = __builtin_amdgcn_mfma_f32_16x16x32_bf16(af0, bfr, acc0, 0, 0, 0);
                if (h < 3) {
                    bf16x8 af1 = *(const bf16x8*)&Ws[((2 * h + 1) * 16 + l16) * APAD + ks * 32 + quad * 8];
                    acc1 = __builtin_amdgcn_mfma_f32_16x16x32_bf16(af1, bfr, acc1, 0, 0, 0);
                }
            }
        }

        // ---- CE epilogue: cross-wave (col-split) combine via LDS ----
        int rl = g * 16 + l16;                       // local row 0..31
        int lab = y[row0 + rl];
        float vv[2][4];
        float vm = -1e30f;
#pragma unroll
        for (int j = 0; j < 2; ++j) {
#pragma unroll
            for (int r = 0; r < 4; ++r) {
                int ct = 2 * h + j;
                int c = ct * 16 + quad * 4 + r;
                float v = (j == 0) ? acc0[r] : acc1[r];
                float bb = (c < L) ? bias[c] : 0.f;
                v += bb;
                vv[j][r] = v;
                bool valid = (c < L) && (j == 0 || h < 3);
                if (valid) vm = fmaxf(vm, v);
            }
        }
        vm = fmaxf(vm, __shfl_xor(vm, 16));
        vm = fmaxf(vm, __shfl_xor(vm, 32));
        if (lane < 16) pmaxs[h * 32 + rl] = vm;
        __syncthreads();
        float M = fmaxf(fmaxf(pmaxs[rl], pmaxs[32 + rl]),
                        fmaxf(pmaxs[64 + rl], pmaxs[96 + rl]));
        float se = 0.f, tv = 0.f;
#pragma unroll
        for (int j = 0; j < 2; ++j) {
#pragma unroll
            for (int r = 0; r < 4; ++r) {
                int ct = 2 * h + j;
                int c = ct * 16 + quad * 4 + r;
                bool valid = (c < L) && (j == 0 || h < 3);
                if (valid) se += __expf(vv[j][r] - M);
                if (valid && c == lab) tv += vv[j][r];
            }
        }
        se += __shfl_xor(se, 16);
        se += __shfl_xor(se, 32);
        tv += __shfl_xor(tv, 16);
        tv += __shfl_xor(tv, 32);
        if (lane < 16) { psums[h * 32 + rl] = se; ptgts[h * 32 + rl] = tv; }
        __syncthreads();
        if (h == 0 && lane < 16) {
            float SE = psums[rl] + psums[32 + rl] + psums[64 + rl] + psums[96 + rl];
            float TV = ptgts[rl] + ptgts[32 + rl] + ptgts[64 + rl] + ptgts[96 + rl];
            float ce = M + __logf(SE) - TV;
            ce += __shfl_xor(ce, 1);
            ce += __shfl_xor(ce, 2);
            ce += __shfl_xor(ce, 4);
            ce += __shfl_xor(ce, 8);
            if (lane == 0) ceg[g] = ce;
        }
        __syncthreads();
        if (t == 0) atomicAdd(ce_accum, ceg[0] + ceg[1]);
    } else {
        int sid = base * 7 + (br - 9);
        if (sid >= NSUM) return;
        // ================= tagged-stream label sums =================
        int* ys = (int*)sm;                                   // 4096 B
        unsigned short* list = (unsigned short*)(sm + 4096);  // 2048 B
        int* cnt4 = (int*)(sm + 4096 + 2048);                 // 16 B
        int* ntot = (int*)(sm + 4096 + 2048 + 16);            // 4 B
        int lg = sid % NSG;
        int bs = (sid / NSG) % SBS;
        int e  = sid / (NSG * SBS);
        int lab0 = lg * SG;

        if (t < SG) cnt4[t] = 0;
        if (t == 8) ntot[0] = 0;
        const int* yb = y + e * B + bs * SRW;
        ys[t] = yb[t];
        ys[t + 512] = yb[t + 512];
        __syncthreads();

        for (int r = t; r < SRW; r += 512) {
            int lb = ys[r] - lab0;
            if ((unsigned)lb < SG) {
                atomicAdd(&cnt4[lb], 1);
                int p = atomicAdd(ntot, 1);
                list[p] = (unsigned short)(r | (lb << 10));
            }
        }
        __syncthreads();
        int n = ntot[0];
        int npad = (n + 3) & ~3;
        if (t < npad - n) list[n + t] = 0;   // pad rows (guarded out below)
        __syncthreads();

        const float* fb = feats + ((size_t)e * B + (size_t)bs * SRW) * F + t * 4;
        float4 a0 = make_float4(0.f, 0.f, 0.f, 0.f);
        float4 a1 = a0, a2 = a0, a3 = a0;

        float4 x[4];
        int tg[4];
        if (n > 0) {
#pragma unroll
            for (int j = 0; j < 4; ++j) {
                int ev = list[j];
                tg[j] = ev >> 10;
                x[j] = *(const float4*)(fb + (size_t)(ev & 1023) * F);
            }
            for (int i = 0; i < npad; i += 4) {
                float4 nx[4];
                int ntg[4];
                if (i + 4 < npad) {
#pragma unroll
                    for (int j = 0; j < 4; ++j) {
                        int ev = list[i + 4 + j];
                        ntg[j] = ev >> 10;
                        nx[j] = *(const float4*)(fb + (size_t)(ev & 1023) * F);
                    }
                }
#pragma unroll
                for (int j = 0; j < 4; ++j) {
                    if (i + j < n) {   // uniform across block
                        float4 v = x[j];
                        int g2 = tg[j];
                        if (g2 == 0)      { a0.x += v.x; a0.y += v.y; a0.z += v.z; a0.w += v.w; }
                        else if (g2 == 1) { a1.x += v.x; a1.y += v.y; a1.z += v.z; a1.w += v.w; }
                        else if (g2 == 2) { a2.x += v.x; a2.y += v.y; a2.z += v.z; a2.w += v.w; }
                        else              { a3.x += v.x; a3.y += v.y; a3.z += v.z; a3.w += v.w; }
                    }
                }
#pragma unroll
                for (int j = 0; j < 4; ++j) { x[j] = nx[j]; tg[j] = ntg[j]; }
            }
        }

        float* pb = partial + (((size_t)e * SBS + bs) * L + lab0) * F + t * 4;
        *(float4*)(pb + 0 * F) = a0;   // unconditional: partial is poisoned
        *(float4*)(pb + 1 * F) = a1;
        *(float4*)(pb + 2 * F) = a2;
        *(float4*)(pb + 3 * F) = a3;
        if (t < SG) atomicAdd(&counts[e * L + lab0 + t], cnt4[t]);
    }
}

// -------- K3: partial[e][bs][l][f] -> per-(e,l) variance over feature dim ---
__global__ void __launch_bounds__(512) k_var(const float* __restrict__ partial,
                                             const int* __restrict__ counts,
                                             float* __restrict__ var_out) {
    int el = blockIdx.x;  // e*L + l
    int e = el / L, l = el % L;
    int t = threadIdx.x;
    float inv = 1.f / fmaxf((float)counts[el], 1.f);
    float4 s = make_float4(0.f, 0.f, 0.f, 0.f);
#pragma unroll
    for (int bs = 0; bs < SBS; ++bs) {
        float4 v = *(const float4*)&partial[(((size_t)e * SBS + bs) * L + l) * F + t * 4];
        s.x += v.x; s.y += v.y; s.z += v.z; s.w += v.w;
    }
    float mx = s.x * inv, my = s.y * inv, mz = s.z * inv, mw = s.w * inv;
    float sm = mx + my + mz + mw;
    float sm2 = mx * mx + my * my + mz * mz + mw * mw;
#pragma unroll
    for (int sft = 1; sft <= 32; sft <<= 1) {
        sm += __shfl_xor(sm, sft);
        sm2 += __shfl_xor(sm2, sft);
    }
    __shared__ float r1[8], r2[8];
    int wv = t >> 6, ln = t & 63;
    if (ln == 0) { r1[wv] = sm; r2[wv] = sm2; }
    __syncthreads();
    if (t == 0) {
        float S = 0.f, S2 = 0.f;
#pragma unroll
        for (int w = 0; w < 8; ++w) { S += r1[w]; S2 += r2[w]; }
        var_out[el] = (S2 - S * S / (float)F) / (float)(F - 1);
    }
}

// ------------------------- K4: final scalar combine -------------------------
__global__ void k_final(const int* __restrict__ counts,
                        const float* __restrict__ var_in,
                        const float* __restrict__ ce_accum,
                        float* __restrict__ out) {
    __shared__ float s_sum[128], s_cnt[128];
    int t = threadIdx.x;
    float selsum = 0.f, selcnt = 0.f;
    for (int l = t; l < L; l += 128) {
        float nvis = 0.f, vsum = 0.f;
        for (int e = 0; e < E; ++e) {
            if (counts[e * L + l] > 0) { nvis += 1.f; vsum += var_in[e * L + l]; }
        }
        float per_label = vsum / fmaxf(nvis, 1.f);
        if (nvis > 1.5f) { selsum += per_label; selcnt += 1.f; }
    }
    s_sum[t] = selsum; s_cnt[t] = selcnt;
    __syncthreads();
    for (int s = 64; s > 0; s >>= 1) {
        if (t < s) { s_sum[t] += s_sum[t + s]; s_cnt[t] += s_cnt[t + s]; }
        __syncthreads();
    }
    if (t == 0) {
        float mean_loss = LAMBDA * s_sum[0] / fmaxf(s_cnt[0], 1.f);
        float ce = ce_accum[0] / (float)NROWS;
        out[0] = mean_loss + ce;
    }
}

extern "C" void kernel_launch(void* const* d_in, const int* in_sizes, int n_in,
                              void* d_out, int out_size, void* d_ws, size_t ws_size,
                              hipStream_t stream) {
    const float* feats = (const float*)d_in[0];
    const int*   y     = (const int*)d_in[1];
    const float* Wm    = (const float*)d_in[2];
    const float* bias  = (const float*)d_in[3];
    float* out = (float*)d_out;

    char* ws = (char*)d_ws;
    float*          ce_accum = (float*)ws;                  // 4 B
    int*            counts   = (int*)(ws + 256);            // 1600 B
    float*          var_buf  = (float*)(ws + 2048);         // 1600 B
    float*          partial  = (float*)(ws + 4096);         // E*SBS*L*F*4 = 26.2 MB
    unsigned short* Wt       = (unsigned short*)(ws + 4096 + (size_t)E * SBS * L * F * 4); // 458 KB

    k_prep<<<F / 64, 256, 0, stream>>>(Wm, Wt, ce_accum, counts);
    k_main<<<NBLK, 512, 0, stream>>>(feats, y, Wt, bias, partial, counts, ce_accum);
    k_var<<<E * L, 512, 0, stream>>>(partial, counts, var_buf);
    k_final<<<1, 128, 0, stream>>>(counts, var_buf, ce_accum, out);
}

// Round 5
// 400.424 us; speedup vs baseline: 1.3111x; 1.0320x over previous
//
#include <hip/hip_runtime.h>
#include <hip/hip_bf16.h>
#include <math.h>

#define E 4
#define B 8192
#define F 2048
#define L 100
#define NROWS (E * B)          // 32768
#define LAMBDA 1.0f

typedef __attribute__((ext_vector_type(8))) short bf16x8;
typedef __attribute__((ext_vector_type(4))) float f32x4;

static __device__ inline unsigned short f2bf(float x) {
    unsigned u = __float_as_uint(x);
    unsigned r = (u + 0x7FFFu + ((u >> 16) & 1u)) >> 16;   // RNE
    return (unsigned short)r;
}

// ---- sums geometry: one block owns (env, 2-label group) fully ----
#define SG 2
#define NSG 50                 // 50 * 2 = 100 labels
#define NCHUNK 8               // 8 sequential chunks of 1024 rows
#define CRW 1024               // rows per chunk
#define NSUMB (E * NSG)        // 200 sum blocks, front-loaded

// ---- gemm geometry (unchanged from R4) ----
#define GBM 32                 // feats rows per block (2 row-groups x 16)
#define GKC 64                 // k-chunk per staging step
#define APAD 72                // LDS row pitch (bf16) for As/Ws
#define NGEMM (NROWS / GBM)    // 1024 units
#define NBLK (NSUMB + NGEMM)   // 1224 blocks

// --------- K1: W[2048][100] f32 -> Wt[112][2048] bf16 (transposed+pad) ------
__global__ void __launch_bounds__(256) k_prep(const float* __restrict__ W,
                                              unsigned short* __restrict__ Wt,
                                              float* __restrict__ ce_accum) {
    __shared__ float st[64][101];
    int t = threadIdx.x;
    int b = blockIdx.x;                      // 32 blocks, 64 k-rows each
    if (b == 0 && t == 0) ce_accum[0] = 0.f;
    int k0 = b * 64;
    for (int i = t; i < 64 * 100; i += 256) {
        st[i / 100][i % 100] = W[(size_t)k0 * L + i];
    }
    __syncthreads();
    for (int i = t; i < 112 * 32; i += 256) {
        int n = i >> 5, kp = i & 31;
        unsigned lo = 0, hi = 0;
        if (n < L) {
            lo = f2bf(st[kp * 2][n]);
            hi = f2bf(st[kp * 2 + 1][n]);
        }
        *(unsigned*)&Wt[(size_t)n * F + k0 + kp * 2] = lo | (hi << 16);
    }
}

// round-half-up pack of two f32 -> packed bf16x2 (hi<<16 | lo)
static __device__ inline unsigned pack_bf(float lo, float hi) {
    unsigned ul = __float_as_uint(lo) + 0x8000u;
    unsigned uh = __float_as_uint(hi) + 0x8000u;
    return __builtin_amdgcn_perm(uh, ul, 0x07060302u);
}

// ---- K2: blocks [0,200) = self-contained label-sum+variance blocks;
// blocks [200,1224) = GEMM+CE (R4 structure: 2 row-groups x 4 col-splits).
__global__ void __launch_bounds__(512, 8) k_main(const float* __restrict__ feats,
                                                 const int* __restrict__ y,
                                                 const unsigned short* __restrict__ Wt,
                                                 const float* __restrict__ bias,
                                                 int* __restrict__ counts,
                                                 float* __restrict__ var_out,
                                                 float* __restrict__ ce_accum) {
    __shared__ __align__(16) char sm[22400];
    int t = threadIdx.x;

    if (blockIdx.x >= NSUMB) {
        int gid = blockIdx.x - NSUMB;
        // =============== GEMM + CE (LDS staged, col-split waves) ===========
        unsigned short* As = (unsigned short*)sm;            // 32*72*2 = 4608
        unsigned short* Ws = As + GBM * APAD;                // 112*72*2 = 16128
        float* pmaxs = (float*)(sm + 20736);                 // [4][32]
        float* psums = pmaxs + 128;                          // [4][32]
        float* ptgts = psums + 128;                          // [4][32]
        float* ceg   = ptgts + 128;                          // [2]
        int wave = t >> 6, lane = t & 63;
        int quad = lane >> 4, l16 = lane & 15;
        int g = wave >> 2, h = wave & 3;                     // row-group, col-split
        size_t row0 = (size_t)gid * GBM;

        // staging map: A: 16 thr/row, 256 B contiguous per row
        int arow = t >> 4, acol = (t & 15) * 4;
        const float* aptr = feats + (row0 + arow) * (size_t)F + acol;
        // W: slot s -> row s>>3, 8 bf16 at (s&7)*8 ; slots t and 512+t
        int w1row = t >> 3, w1c = (t & 7) * 8;
        int w2row = (512 + t) >> 3, w2c = ((512 + t) & 7) * 8;
        const unsigned short* wp1 = Wt + (size_t)w1row * F + w1c;
        const unsigned short* wp2 = (t < 384) ? Wt + (size_t)w2row * F + w2c : Wt;

        f32x4 acc0 = (f32x4){0.f, 0.f, 0.f, 0.f};
        f32x4 acc1 = acc0;

        float4 pa = *(const float4*)aptr;
        uint4 pw1 = *(const uint4*)wp1;
        uint4 pw2 = *(const uint4*)wp2;

        for (int k0 = 0; k0 < F; k0 += GKC) {
            __syncthreads();                 // readers of prev tile done
            unsigned u0 = pack_bf(pa.x, pa.y), u1 = pack_bf(pa.z, pa.w);
            *(uint2*)&As[arow * APAD + acol] = make_uint2(u0, u1);
            *(uint4*)&Ws[w1row * APAD + w1c] = pw1;
            if (t < 384) *(uint4*)&Ws[w2row * APAD + w2c] = pw2;
            __syncthreads();
            if (k0 + GKC < F) {              // prefetch next tile into regs
                pa  = *(const float4*)(aptr + k0 + GKC);
                pw1 = *(const uint4*)(wp1 + k0 + GKC);
                pw2 = *(const uint4*)(wp2 + k0 + GKC);
            }
#pragma unroll
            for (int ks = 0; ks < 2; ++ks) {
                bf16x8 bfr = *(const bf16x8*)&As[(g * 16 + l16) * APAD + ks * 32 + quad * 8];
                bf16x8 af0 = *(const bf16x8*)&Ws[((2 * h) * 16 + l16) * APAD + ks * 32 + quad * 8];
                acc0 = __builtin_amdgcn_mfma_f32_16x16x32_bf16(af0, bfr, acc0, 0, 0, 0);
                if (h < 3) {
                    bf16x8 af1 = *(const bf16x8*)&Ws[((2 * h + 1) * 16 + l16) * APAD + ks * 32 + quad * 8];
                    acc1 = __builtin_amdgcn_mfma_f32_16x16x32_bf16(af1, bfr, acc1, 0, 0, 0);
                }
            }
        }

        // ---- CE epilogue: cross-wave (col-split) combine via LDS ----
        int rl = g * 16 + l16;                       // local row 0..31
        int lab = y[row0 + rl];
        float vv[2][4];
        float vm = -1e30f;
#pragma unroll
        for (int j = 0; j < 2; ++j) {
#pragma unroll
            for (int r = 0; r < 4; ++r) {
                int ct = 2 * h + j;
                int c = ct * 16 + quad * 4 + r;
                float v = (j == 0) ? acc0[r] : acc1[r];
                float bb = (c < L) ? bias[c] : 0.f;
                v += bb;
                vv[j][r] = v;
                bool valid = (c < L) && (j == 0 || h < 3);
                if (valid) vm = fmaxf(vm, v);
            }
        }
        vm = fmaxf(vm, __shfl_xor(vm, 16));
        vm = fmaxf(vm, __shfl_xor(vm, 32));
        if (lane < 16) pmaxs[h * 32 + rl] = vm;
        __syncthreads();
        float M = fmaxf(fmaxf(pmaxs[rl], pmaxs[32 + rl]),
                        fmaxf(pmaxs[64 + rl], pmaxs[96 + rl]));
        float se = 0.f, tv = 0.f;
#pragma unroll
        for (int j = 0; j < 2; ++j) {
#pragma unroll
            for (int r = 0; r < 4; ++r) {
                int ct = 2 * h + j;
                int c = ct * 16 + quad * 4 + r;
                bool valid = (c < L) && (j == 0 || h < 3);
                if (valid) se += __expf(vv[j][r] - M);
                if (valid && c == lab) tv += vv[j][r];
            }
        }
        se += __shfl_xor(se, 16);
        se += __shfl_xor(se, 32);
        tv += __shfl_xor(tv, 16);
        tv += __shfl_xor(tv, 32);
        if (lane < 16) { psums[h * 32 + rl] = se; ptgts[h * 32 + rl] = tv; }
        __syncthreads();
        if (h == 0 && lane < 16) {
            float SE = psums[rl] + psums[32 + rl] + psums[64 + rl] + psums[96 + rl];
            float TV = ptgts[rl] + ptgts[32 + rl] + ptgts[64 + rl] + ptgts[96 + rl];
            float ce = M + __logf(SE) - TV;
            ce += __shfl_xor(ce, 1);
            ce += __shfl_xor(ce, 2);
            ce += __shfl_xor(ce, 4);
            ce += __shfl_xor(ce, 8);
            if (lane == 0) ceg[g] = ce;
        }
        __syncthreads();
        if (t == 0) atomicAdd(ce_accum, ceg[0] + ceg[1]);
    } else {
        // ====== self-contained label sums + variance: (env, 2 labels) ======
        int sid = blockIdx.x;                 // 0..199
        int lg = sid % NSG;
        int e  = sid / NSG;
        int lab0 = lg * SG;

        int* ys = (int*)sm;                                   // 4096 B
        unsigned short* list = (unsigned short*)(sm + 4096);  // 2048 B
        int* cnt2 = (int*)(sm + 6144);                        // 8 B
        int* ntot = (int*)(sm + 6144 + 8);                    // 4 B
        int* cntT = (int*)(sm + 6144 + 16);                   // 8 B
        float* rr  = (float*)(sm + 6144 + 32);                // 32 floats

        if (t < SG) cntT[t] = 0;

        // each thread owns 4 consecutive features (512*4 = 2048)
        float4 a0 = make_float4(0.f, 0.f, 0.f, 0.f);
        float4 a1 = a0;

        for (int c = 0; c < NCHUNK; ++c) {
            __syncthreads();                  // list/ys reuse + cntT init
            if (t < SG) cnt2[t] = 0;
            if (t == 8) ntot[0] = 0;
            const int* yb = y + e * B + c * CRW;
            ys[t] = yb[t];
            ys[t + 512] = yb[t + 512];
            __syncthreads();

            for (int r = t; r < CRW; r += 512) {
                int lb = ys[r] - lab0;
                if ((unsigned)lb < SG) {
                    atomicAdd(&cnt2[lb], 1);
                    int p = atomicAdd(ntot, 1);
                    list[p] = (unsigned short)(r | (lb << 10));
                }
            }
            __syncthreads();
            int n = ntot[0];
            if (t < SG) cntT[t] += cnt2[t];
            int npad = (n + 3) & ~3;
            if (t < npad - n) list[n + t] = 0;   // pad rows (guarded below)
            __syncthreads();
            if (n == 0) continue;

            const float* fb = feats + ((size_t)e * B + (size_t)c * CRW) * F + t * 4;
            float4 x[4];
            int tg[4];
#pragma unroll
            for (int j = 0; j < 4; ++j) {
                int ev = list[j];
                tg[j] = ev >> 10;
                x[j] = *(const float4*)(fb + (size_t)(ev & 1023) * F);
            }
            for (int i = 0; i < npad; i += 4) {
                float4 nx[4];
                int ntg[4];
                if (i + 4 < npad) {
#pragma unroll
                    for (int j = 0; j < 4; ++j) {
                        int ev = list[i + 4 + j];
                        ntg[j] = ev >> 10;
                        nx[j] = *(const float4*)(fb + (size_t)(ev & 1023) * F);
                    }
                }
#pragma unroll
                for (int j = 0; j < 4; ++j) {
                    if (i + j < n) {   // uniform across block
                        float4 v = x[j];
                        if (tg[j] == 0) { a0.x += v.x; a0.y += v.y; a0.z += v.z; a0.w += v.w; }
                        else            { a1.x += v.x; a1.y += v.y; a1.z += v.z; a1.w += v.w; }
                    }
                }
#pragma unroll
                for (int j = 0; j < 4; ++j) { x[j] = nx[j]; tg[j] = ntg[j]; }
            }
        }
        __syncthreads();

        // ---- per-label variance over feature dim (inlined old k_var) ----
        float inv0 = 1.f / fmaxf((float)cntT[0], 1.f);
        float inv1 = 1.f / fmaxf((float)cntT[1], 1.f);
        float m0x = a0.x * inv0, m0y = a0.y * inv0, m0z = a0.z * inv0, m0w = a0.w * inv0;
        float m1x = a1.x * inv1, m1y = a1.y * inv1, m1z = a1.z * inv1, m1w = a1.w * inv1;
        float s0 = m0x + m0y + m0z + m0w;
        float q0 = m0x * m0x + m0y * m0y + m0z * m0z + m0w * m0w;
        float s1 = m1x + m1y + m1z + m1w;
        float q1 = m1x * m1x + m1y * m1y + m1z * m1z + m1w * m1w;
#pragma unroll
        for (int sft = 1; sft <= 32; sft <<= 1) {
            s0 += __shfl_xor(s0, sft);
            q0 += __shfl_xor(q0, sft);
            s1 += __shfl_xor(s1, sft);
            q1 += __shfl_xor(q1, sft);
        }
        int wv = t >> 6, ln = t & 63;
        if (ln == 0) {
            rr[wv] = s0; rr[8 + wv] = q0; rr[16 + wv] = s1; rr[24 + wv] = q1;
        }
        __syncthreads();
        if (t == 0) {
            float S0 = 0.f, Q0 = 0.f, S1 = 0.f, Q1 = 0.f;
#pragma unroll
            for (int w = 0; w < 8; ++w) {
                S0 += rr[w]; Q0 += rr[8 + w]; S1 += rr[16 + w]; Q1 += rr[24 + w];
            }
            var_out[e * L + lab0]     = (Q0 - S0 * S0 / (float)F) / (float)(F - 1);
            var_out[e * L + lab0 + 1] = (Q1 - S1 * S1 / (float)F) / (float)(F - 1);
            counts[e * L + lab0]     = cntT[0];   // direct store: sole owner
            counts[e * L + lab0 + 1] = cntT[1];
        }
    }
}

// ------------------------- K4: final scalar combine -------------------------
__global__ void k_final(const int* __restrict__ counts,
                        const float* __restrict__ var_in,
                        const float* __restrict__ ce_accum,
                        float* __restrict__ out) {
    __shared__ float s_sum[128], s_cnt[128];
    int t = threadIdx.x;
    float selsum = 0.f, selcnt = 0.f;
    for (int l = t; l < L; l += 128) {
        float nvis = 0.f, vsum = 0.f;
        for (int e = 0; e < E; ++e) {
            if (counts[e * L + l] > 0) { nvis += 1.f; vsum += var_in[e * L + l]; }
        }
        float per_label = vsum / fmaxf(nvis, 1.f);
        if (nvis > 1.5f) { selsum += per_label; selcnt += 1.f; }
    }
    s_sum[t] = selsum; s_cnt[t] = selcnt;
    __syncthreads();
    for (int s = 64; s > 0; s >>= 1) {
        if (t < s) { s_sum[t] += s_sum[t + s]; s_cnt[t] += s_cnt[t + s]; }
        __syncthreads();
    }
    if (t == 0) {
        float mean_loss = LAMBDA * s_sum[0] / fmaxf(s_cnt[0], 1.f);
        float ce = ce_accum[0] / (float)NROWS;
        out[0] = mean_loss + ce;
    }
}

extern "C" void kernel_launch(void* const* d_in, const int* in_sizes, int n_in,
                              void* d_out, int out_size, void* d_ws, size_t ws_size,
                              hipStream_t stream) {
    const float* feats = (const float*)d_in[0];
    const int*   y     = (const int*)d_in[1];
    const float* Wm    = (const float*)d_in[2];
    const float* bias  = (const float*)d_in[3];
    float* out = (float*)d_out;

    char* ws = (char*)d_ws;
    float*          ce_accum = (float*)ws;                  // 4 B
    int*            counts   = (int*)(ws + 256);            // 1600 B
    float*          var_buf  = (float*)(ws + 2048);         // 1600 B
    unsigned short* Wt       = (unsigned short*)(ws + 4096); // 458 KB

    k_prep<<<F / 64, 256, 0, stream>>>(Wm, Wt, ce_accum);
    k_main<<<NBLK, 512, 0, stream>>>(feats, y, Wt, bias, counts, var_buf, ce_accum);
    k_final<<<1, 128, 0, stream>>>(counts, var_buf, ce_accum, out);
}